// Round 8
// baseline (1099.567 us; speedup 1.0000x reference)
//
#include <hip/hip_runtime.h>

typedef unsigned short ushort_t;
typedef unsigned long long u64;
typedef short short8 __attribute__((ext_vector_type(8)));
typedef float f32x4 __attribute__((ext_vector_type(4)));

#define B_   32
#define C_   64
#define T_   12
#define N_   1024
#define KS_  3
#define KC_  3072
#define RPB  768
#define NT_  48          // K-tiles of 64
#define BM_  192
#define LBUF 24576       // bytes per LDS buffer: A only, 192*64*2

__device__ __forceinline__ float bf2f(ushort_t u) {
  union { unsigned u; float f; } v; v.u = ((unsigned)u) << 16; return v.f;
}
__device__ __forceinline__ ushort_t f2bf(float f) {
  union { float f; unsigned u; } v; v.f = f;
  unsigned r = v.u + 0x7FFFu + ((v.u >> 16) & 1u);
  return (ushort_t)(r >> 16);
}

__device__ __forceinline__ void gload16(const ushort_t* g, ushort_t* l) {
  __builtin_amdgcn_global_load_lds(
      (const __attribute__((address_space(1))) unsigned int*)g,
      (__attribute__((address_space(3))) unsigned int*)l, 16, 0, 0);
}

// ---------- prep: thA[l][k][o][i] = bf16(theta_l[i][o][k]) ----------
__global__ void prep_th(const float* __restrict__ th1, const float* __restrict__ th2,
                        ushort_t* __restrict__ out) {
  int id = blockIdx.x * 256 + threadIdx.x;          // 2*3*64*64 = 24576
  if (id >= 24576) return;
  int l = id / 12288, rem = id % 12288;
  int k = rem / 4096;
  int o = (rem >> 6) & 63;
  int i = rem & 63;
  const float* th = l ? th2 : th1;
  out[id] = f2bf(th[(i * 64 + o) * 3 + k]);
}

// ---------- prep: Bt2 fragment-packed B for direct global->reg MFMA loads ----------
// Bt2 flat[((nb*96 + ksg)*64 + lane)*8 + j] = bf16(Bt[n][kc]) with
//   n = nb*16 + (lane&15), kc = ksg*32 + (lane>>4)*8 + j, Bt[n][kc] = Lk[kc>>10][n][kc&1023].
// A wave's dwordx4 load at lane*16B is a fully coalesced 1KB segment = one (16n x 32k) fragment.
__global__ void prep_bt(const float* __restrict__ Lk, ushort_t* __restrict__ Bt2) {
  int c = blockIdx.x * 256 + threadIdx.x;           // 393216
  int L = c & 63;
  int ksg = (c >> 6) % 96;
  int nb = c / (96 * 64);
  int n = nb * 16 + (L & 15);
  int kc = ksg * 32 + (L >> 4) * 8;
  int k = kc >> 10, m = kc & 1023;
  const float* src = Lk + ((size_t)k * N_ + n) * N_ + m;
  float4 v0 = *(const float4*)src;
  float4 v1 = *(const float4*)(src + 4);
  short8 o8;
  o8[0] = (short)f2bf(v0.x); o8[1] = (short)f2bf(v0.y);
  o8[2] = (short)f2bf(v0.z); o8[3] = (short)f2bf(v0.w);
  o8[4] = (short)f2bf(v1.x); o8[5] = (short)f2bf(v1.y);
  o8[6] = (short)f2bf(v1.z); o8[7] = (short)f2bf(v1.w);
  *(short8*)&Bt2[(size_t)c * 8] = o8;
}

// ---------- MFMA channel mix ----------
template<int IN_BF16>
__global__ __launch_bounds__(256, 2)
void mix_mfma(const void* __restrict__ in, const ushort_t* __restrict__ thA,
              ushort_t* __restrict__ Y, int b0) {
  const int bid = blockIdx.x;           // nb*48: [bt][mq]
  const int mq = bid & 3;
  const int bt = bid >> 2;              // bl*12 + t
  const int bl = bt / 12, t = bt % 12;
  const int b = b0 + bl;
  const int tid = threadIdx.x;
  const int wv = tid >> 6, lane = tid & 63;
  const int l15 = lane & 15, l4 = lane >> 4;
  const int m0 = mq * 256 + wv * 64;

  const ushort_t* xg_b = (const ushort_t*)in;
  const float*    xg_f = (const float*)in;

  short8 bfr[4][2];
  #pragma unroll
  for (int mf = 0; mf < 4; ++mf) {
    const int m = m0 + mf * 16 + l15;
    #pragma unroll
    for (int ks = 0; ks < 2; ++ks) {
      #pragma unroll
      for (int j = 0; j < 8; ++j) {
        const int i = ks * 32 + l4 * 8 + j;
        const size_t adr = ((size_t)(b * C_ + i) * T_ + t) * N_ + m;
        ushort_t v = IN_BF16 ? xg_b[adr] : f2bf(xg_f[adr]);
        bfr[mf][ks][j] = (short)v;
      }
    }
  }

  const size_t rbase = (size_t)(bt * C_);
  #pragma unroll
  for (int k = 0; k < 3; ++k) {
    short8 afr[4][2];
    #pragma unroll
    for (int of = 0; of < 4; ++of)
      #pragma unroll
      for (int ks = 0; ks < 2; ++ks)
        afr[of][ks] = *(const short8*)&thA[(size_t)(k * 64 + of * 16 + l15) * 64 + ks * 32 + l4 * 8];

    f32x4 acc[4][4] = {};
    #pragma unroll
    for (int ks = 0; ks < 2; ++ks)
      #pragma unroll
      for (int of = 0; of < 4; ++of)
        #pragma unroll
        for (int mf = 0; mf < 4; ++mf)
          acc[of][mf] = __builtin_amdgcn_mfma_f32_16x16x32_bf16(afr[of][ks], bfr[mf][ks], acc[of][mf], 0, 0, 0);

    #pragma unroll
    for (int of = 0; of < 4; ++of)
      #pragma unroll
      for (int mf = 0; mf < 4; ++mf)
        #pragma unroll
        for (int r = 0; r < 4; ++r) {
          const int o = of * 16 + l4 * 4 + r;
          Y[(rbase + o) * KC_ + k * N_ + m0 + mf * 16 + l15] = f2bf(acc[of][mf][r]);
        }
  }
}

// ---------- 192x256-tile GEMM, A via LDS (swizzled), B direct global->reg ----------
// 2 phases / K-tile, 2 barriers / K-tile:
//  PH0(u): read A-s1(u) ds; load B-s1(u) glb; MFMA s0(u) [as0,bs0 prefetched];
//          lgkm0; BARRIER alpha  (seals buf[u&1]: s0 reads drained in ph1(u-1), s1 here)
//  PH1(u): stage A(u+2)->buf[u&1]; load B-s0(u+1) glb; vmcnt(8) [drains A(u+1), ledger-
//          verified incl. tail]; BARRIER beta (A(u+1) visible to all); read A-s0(u+1) ds;
//          MFMA s1(u); lgkm0.
// Register double-buffer: as0/asx (cross-iter), bs0/bsx (one phase ahead).

#define MFMA24(A, Bv)                                                           \
  _Pragma("unroll") for (int m_ = 0; m_ < 6; ++m_)                              \
    _Pragma("unroll") for (int n_ = 0; n_ < 4; ++n_)                            \
      acc[m_][n_] = __builtin_amdgcn_mfma_f32_16x16x32_bf16(A[m_], Bv[n_], acc[m_][n_], 0, 0, 0);

#define STAGE_AP(kt, PAR, j) gload16(gA##j + (size_t)(kt) * 64,                 \
    (ushort_t*)(lp + ((PAR) ? LBUF : 0) + (j) * 8192 + wofs))

#define LD8(p) (*(const short8*)(p))

#define ITER(U, PAR, AS0, AS1, AS0N, BS0, BS1, BS0N) do {                       \
    const char* abp = lp + ((PAR) ? LBUF : 0) + a_base;                         \
    const char* abn = lp + ((PAR) ? 0 : LBUF) + a_base;                         \
    /* ---- PH0 ---- */                                                         \
    AS1[0] = LD8(abp + 12288);        AS1[1] = LD8(abp + 12288 + 2048);         \
    AS1[2] = LD8(abp + 12288 + 4096); AS1[3] = LD8(abp + 12288 + 6144);         \
    AS1[4] = LD8(abp + 12288 + 8192); AS1[5] = LD8(abp + 12288 + 10240);        \
    BS1[0] = LD8(bb0 + (size_t)(2 * (U) + 1) * 512);                            \
    BS1[1] = LD8(bb1 + (size_t)(2 * (U) + 1) * 512);                            \
    BS1[2] = LD8(bb2 + (size_t)(2 * (U) + 1) * 512);                            \
    BS1[3] = LD8(bb3 + (size_t)(2 * (U) + 1) * 512);                            \
    __builtin_amdgcn_s_setprio(1);                                              \
    MFMA24(AS0, BS0)                                                            \
    __builtin_amdgcn_s_setprio(0);                                              \
    asm volatile("s_waitcnt lgkmcnt(0)" ::: "memory");                          \
    __builtin_amdgcn_sched_barrier(0);                                          \
    __builtin_amdgcn_s_barrier();       /* alpha: buf[PAR] sealed */            \
    __builtin_amdgcn_sched_barrier(0);                                          \
    /* ---- PH1 ---- */                                                         \
    if ((U) + 2 < NT_) { STAGE_AP((U) + 2, PAR, 0); STAGE_AP((U) + 2, PAR, 1);  \
                         STAGE_AP((U) + 2, PAR, 2); }                           \
    if ((U) + 1 < NT_) {                                                        \
      BS0N[0] = LD8(bb0 + (size_t)(2 * (U) + 2) * 512);                         \
      BS0N[1] = LD8(bb1 + (size_t)(2 * (U) + 2) * 512);                         \
      BS0N[2] = LD8(bb2 + (size_t)(2 * (U) + 2) * 512);                         \
      BS0N[3] = LD8(bb3 + (size_t)(2 * (U) + 2) * 512);                         \
    }                                                                           \
    asm volatile("s_waitcnt vmcnt(8)" ::: "memory");                            \
    __builtin_amdgcn_sched_barrier(0);                                          \
    __builtin_amdgcn_s_barrier();       /* beta: A(U+1) visible to all */       \
    __builtin_amdgcn_sched_barrier(0);                                          \
    if ((U) + 1 < NT_) {                                                        \
      AS0N[0] = LD8(abn);          AS0N[1] = LD8(abn + 2048);                   \
      AS0N[2] = LD8(abn + 4096);   AS0N[3] = LD8(abn + 6144);                   \
      AS0N[4] = LD8(abn + 8192);   AS0N[5] = LD8(abn + 10240);                  \
    }                                                                           \
    __builtin_amdgcn_s_setprio(1);                                              \
    MFMA24(AS1, BS1)                                                            \
    __builtin_amdgcn_s_setprio(0);                                              \
    asm volatile("s_waitcnt lgkmcnt(0)" ::: "memory");                          \
    __builtin_amdgcn_sched_barrier(0);                                          \
  } while (0)

template<int RES_BF16>
__global__ __launch_bounds__(512, 2)
void gemm8p(const ushort_t* __restrict__ Y, const ushort_t* __restrict__ Bt2,
            const void* __restrict__ res, const float* __restrict__ bias,
            ushort_t* __restrict__ outb, int batch0) {
  // bijective XCD swizzle; gridDim.x = 16*nb is always a multiple of 8
  const int nwg = gridDim.x;
  int orig = blockIdx.x;
  int q8 = nwg >> 3;
  int wg = (orig & 7) * q8 + (orig >> 3);
  const int mtile = wg >> 2, ntile = wg & 3;

  const int tid = threadIdx.x;
  const int wid = tid >> 6, lane = tid & 63;
  const int wm = wid >> 2, wn = wid & 3;
  const int l15 = lane & 15, l4 = lane >> 4;

  __shared__ ushort_t LDSU[LBUF];   // 49152 bytes (2 x 24576 A buffers)
  char* lp = (char*)LDSU;

  const int row0 = mtile * BM_;
  const int n0 = ntile * 256;
  const int wofs = wid * 1024;

  // A staging source pointers (per-lane, swizzle pre-applied on global col)
  const int lam = lane >> 2, lc = lane & 3;
  const ushort_t *gA0, *gA1, *gA2;
  {
    int p, s, row, colel;
    p = 0 * 128 + wid * 16 + lam; s = p >= 192 ? 1 : 0; row = p - s * 192;
    colel = (lc * 8) ^ (((row >> 3) & 1) << 4);
    gA0 = Y + (size_t)(row0 + row) * KC_ + s * 32 + colel;
    p = 1 * 128 + wid * 16 + lam; s = p >= 192 ? 1 : 0; row = p - s * 192;
    colel = (lc * 8) ^ (((row >> 3) & 1) << 4);
    gA1 = Y + (size_t)(row0 + row) * KC_ + s * 32 + colel;
    p = 2 * 128 + wid * 16 + lam; s = p >= 192 ? 1 : 0; row = p - s * 192;
    colel = (lc * 8) ^ (((row >> 3) & 1) << 4);
    gA2 = Y + (size_t)(row0 + row) * KC_ + s * 32 + colel;
  }

  // B fragment bases (direct global->reg; lane slot = l4*16+l15 matches MFMA layout)
  const int nb0 = ntile * 16;
  const ushort_t* bb0 = Bt2 + (size_t)(nb0 + wn)      * 49152 + lane * 8;
  const ushort_t* bb1 = Bt2 + (size_t)(nb0 + wn + 4)  * 49152 + lane * 8;
  const ushort_t* bb2 = Bt2 + (size_t)(nb0 + wn + 8)  * 49152 + lane * 8;
  const ushort_t* bb3 = Bt2 + (size_t)(nb0 + wn + 12) * 49152 + lane * 8;

  // A read-side lane byte base (swizzle XOR on col)
  const int swz = ((l15 >> 3) & 1) << 5;
  const int a_base = (wm * 16 + l15) * 64 + ((l4 * 16) ^ swz);

  // prologue: stage A tiles 0,1; load B s0(0); wait tile0; read A-s0(0)
  STAGE_AP(0, 0, 0); STAGE_AP(0, 0, 1); STAGE_AP(0, 0, 2);
  STAGE_AP(1, 1, 0); STAGE_AP(1, 1, 1); STAGE_AP(1, 1, 2);
  short8 as0[6], as1[6], asx[6], bs0[4], bs1[4], bsx[4];
  bs0[0] = LD8(bb0); bs0[1] = LD8(bb1); bs0[2] = LD8(bb2); bs0[3] = LD8(bb3);
  asm volatile("s_waitcnt vmcnt(7)" ::: "memory");   // A(0) landed
  __builtin_amdgcn_sched_barrier(0);
  __builtin_amdgcn_s_barrier();
  __builtin_amdgcn_sched_barrier(0);
  as0[0] = LD8(lp + a_base);         as0[1] = LD8(lp + a_base + 2048);
  as0[2] = LD8(lp + a_base + 4096);  as0[3] = LD8(lp + a_base + 6144);
  as0[4] = LD8(lp + a_base + 8192);  as0[5] = LD8(lp + a_base + 10240);

  f32x4 acc[6][4] = {};

  for (int uu = 0; uu < NT_; uu += 2) {
    ITER(uu,     0, as0, as1, asx, bs0, bs1, bsx);
    ITER(uu + 1, 1, asx, as1, as0, bsx, bs1, bs0);
  }

  // epilogue: bias + residual + relu, bf16 store
  const float*    resf = (const float*)res;
  const ushort_t* resb = (const ushort_t*)res;
  const int gb = batch0 + (mtile >> 2);
  const int rowb0 = (mtile & 3) * BM_;
  const int colb = n0 + wn * 16 + l15;
  #pragma unroll
  for (int mf = 0; mf < 6; ++mf) {
    #pragma unroll
    for (int r = 0; r < 4; ++r) {
      int rl = mf * 32 + wm * 16 + l4 * 4 + r;
      int rowb = rowb0 + rl;
      int t = rowb >> 6, o = rowb & 63;
      float bs = bias[o];
      size_t base = ((size_t)(gb * C_ + o) * T_ + t) * N_;
      #pragma unroll
      for (int nf = 0; nf < 4; ++nf) {
        int col = colb + nf * 64;
        float rv = RES_BF16 ? bf2f(resb[base + col]) : resf[base + col];
        float v = acc[mf][nf][r] + bs + rv;
        v = fmaxf(v, 0.0f);
        outb[base + col] = f2bf(v);
      }
    }
  }
}

// ---------- FC: out[b,t,n,o2] = sum_o fw[o2,o]*x2[b,o,t,n] + fb[o2] ----------
__global__ __launch_bounds__(256, 2)
void fc_kernel(const ushort_t* __restrict__ x2, const float* __restrict__ fw,
               const float* __restrict__ fb, float* __restrict__ out) {
  int bid = blockIdx.x;
  int nt = bid & 15, btid = bid >> 4;
  int t = btid % 12, b = btid / 12;
  int n0 = nt << 6;
  int tid = threadIdx.x;
  __shared__ float xt[64 * 64];
  __shared__ float wl[64 * 64];
  #pragma unroll
  for (int j = 0; j < 2; ++j) {
    int c = tid + j * 256;
    int row = c >> 3, col = (c & 7) << 3;
    short8 v = *(const short8*)&x2[((b * C_ + row) * T_ + t) * N_ + n0 + col];
    #pragma unroll
    for (int q = 0; q < 8; ++q) xt[row * 64 + col + q] = bf2f((ushort_t)v[q]);
  }
  #pragma unroll
  for (int j = 0; j < 4; ++j) {
    int c = tid + j * 256;
    int o2 = c >> 4, o4 = (c & 15) << 2;
    float4 v = *(const float4*)&fw[o2 * 64 + o4];
    wl[(o4 + 0) * 64 + o2] = v.x; wl[(o4 + 1) * 64 + o2] = v.y;
    wl[(o4 + 2) * 64 + o2] = v.z; wl[(o4 + 3) * 64 + o2] = v.w;
  }
  __syncthreads();
  int p = tid & 31, ng = tid >> 5;
  float a0[8] = {}, a1[8] = {};
  for (int o = 0; o < 64; ++o) {
    float w0 = wl[o * 64 + p], w1 = wl[o * 64 + p + 32];
    float4 xa = *(const float4*)&xt[o * 64 + ng * 8];
    float4 xb = *(const float4*)&xt[o * 64 + ng * 8 + 4];
    float xv[8] = {xa.x, xa.y, xa.z, xa.w, xb.x, xb.y, xb.z, xb.w};
    #pragma unroll
    for (int j = 0; j < 8; ++j) { a0[j] = fmaf(w0, xv[j], a0[j]); a1[j] = fmaf(w1, xv[j], a1[j]); }
  }
  float fb0 = fb[p], fb1 = fb[p + 32];
  int obase = (b * T_ + t) * N_ + n0 + ng * 8;
  #pragma unroll
  for (int j = 0; j < 8; ++j) {
    out[(obase + j) * 64 + p]      = a0[j] + fb0;
    out[(obase + j) * 64 + p + 32] = a1[j] + fb1;
  }
}

extern "C" void kernel_launch(void* const* d_in, const int* in_sizes, int n_in,
                              void* d_out, int out_size, void* d_ws, size_t ws_size,
                              hipStream_t stream) {
  const float* x   = (const float*)d_in[0];
  const float* Lk  = (const float*)d_in[1];
  const float* th1 = (const float*)d_in[2];
  const float* b1  = (const float*)d_in[3];
  const float* th2 = (const float*)d_in[4];
  const float* b2  = (const float*)d_in[5];
  const float* fcw = (const float*)d_in[6];
  const float* fcb = (const float*)d_in[7];

  char* ws = (char*)d_ws;
  size_t off = 0;
  auto alloc = [&](size_t bytes) { size_t p = off; off += (bytes + 255) & ~(size_t)255; return p; };
  size_t oBt = alloc((size_t)KC_ * N_ * 2);
  size_t oTh = alloc((size_t)2 * 3 * 64 * 64 * 2);
  size_t oX2 = alloc((size_t)B_ * C_ * T_ * N_ * 2);
  size_t perB = (size_t)RPB * KC_ * 2;
  size_t avail = ws_size > off ? ws_size - off : 0;
  int NB = (int)(avail / perB);
  if (NB > B_) NB = B_;
  if (NB < 1) NB = 1;

  ushort_t* Bt2 = (ushort_t*)(ws + oBt);
  ushort_t* Th  = (ushort_t*)(ws + oTh);
  ushort_t* X2  = (ushort_t*)(ws + oX2);
  ushort_t* Yb  = (ushort_t*)(ws + off);
  ushort_t* X1  = (ushort_t*)d_out;

  prep_th<<<96, 256, 0, stream>>>(th1, th2, Th);
  prep_bt<<<1536, 256, 0, stream>>>(Lk, Bt2);

  for (int b0 = 0; b0 < B_; b0 += NB) {
    int nb = (b0 + NB <= B_) ? NB : (B_ - b0);
    mix_mfma<0><<<nb * 48, 256, 0, stream>>>((const void*)x, Th, Yb, b0);
    gemm8p<0><<<dim3(16 * nb), 512, 0, stream>>>(Yb, Bt2, (const void*)x, b1, X1, b0);
  }
  for (int b0 = 0; b0 < B_; b0 += NB) {
    int nb = (b0 + NB <= B_) ? NB : (B_ - b0);
    mix_mfma<1><<<nb * 48, 256, 0, stream>>>((const void*)X1, Th + 12288, Yb, b0);
    gemm8p<1><<<dim3(16 * nb), 512, 0, stream>>>(Yb, Bt2, (const void*)X1, b2, X2, b0);
  }
  fc_kernel<<<32 * 12 * 16, 256, 0, stream>>>(X2, fcw, fcb, (float*)d_out);
}

// Round 9
// 537.339 us; speedup vs baseline: 2.0463x; 2.0463x over previous
//
#include <hip/hip_runtime.h>

typedef unsigned short ushort_t;
typedef unsigned long long u64;
typedef short short8 __attribute__((ext_vector_type(8)));
typedef float f32x4 __attribute__((ext_vector_type(4)));
typedef float f32x16 __attribute__((ext_vector_type(16)));

#define B_   32
#define C_   64
#define T_   12
#define N_   1024
#define KS_  3
#define KC_  3072
#define RPB  768
#define NT_  48          // K-tiles of 64
#define BM_  192
#define LBUF 57344       // BYTES per LDS buffer: A 24576 + B 32768
#define ABYT 24576       // A region bytes

__device__ __forceinline__ float bf2f(ushort_t u) {
  union { unsigned u; float f; } v; v.u = ((unsigned)u) << 16; return v.f;
}
__device__ __forceinline__ ushort_t f2bf(float f) {
  union { float f; unsigned u; } v; v.f = f;
  unsigned r = v.u + 0x7FFFu + ((v.u >> 16) & 1u);
  return (ushort_t)(r >> 16);
}

__device__ __forceinline__ void gload16(const ushort_t* g, ushort_t* l) {
  __builtin_amdgcn_global_load_lds(
      (const __attribute__((address_space(1))) unsigned int*)g,
      (__attribute__((address_space(3))) unsigned int*)l, 16, 0, 0);
}

// ---------- prep: thA[l][k][o][i] = bf16(theta_l[i][o][k]) ----------
__global__ void prep_th(const float* __restrict__ th1, const float* __restrict__ th2,
                        ushort_t* __restrict__ out) {
  int id = blockIdx.x * 256 + threadIdx.x;          // 2*3*64*64 = 24576
  if (id >= 24576) return;
  int l = id / 12288, rem = id % 12288;
  int k = rem / 4096;
  int o = (rem >> 6) & 63;
  int i = rem & 63;
  const float* th = l ? th2 : th1;
  out[id] = f2bf(th[(i * 64 + o) * 3 + k]);
}

// ---------- prep: Bt2 fragment-packed B for 32x32x16 MFMA ----------
// Bt2[((cg*192 + ksg)*64 + lane)*8 + e] = bf16( Bt[n][kc] ),
//   n = cg*32 + (lane&31), kc = ksg*16 + (lane>>5)*8 + e, Bt[n][kc] = Lk[kc>>10][n][kc&1023].
// One wave's 1KB lane-contiguous segment = one (32n x 16k) B fragment.
__global__ void prep_bt(const float* __restrict__ Lk, ushort_t* __restrict__ Bt2) {
  int c = blockIdx.x * 256 + threadIdx.x;           // 32*192*64 = 393216
  int lane = c & 63;
  int ksg = (c >> 6) % 192;
  int cg  = c / (192 * 64);
  int n  = cg * 32 + (lane & 31);
  int kc = ksg * 16 + (lane >> 5) * 8;
  int kpl = kc >> 10, m = kc & 1023;
  const float* src = Lk + ((size_t)kpl * N_ + n) * N_ + m;
  float4 v0 = *(const float4*)src;
  float4 v1 = *(const float4*)(src + 4);
  short8 o8;
  o8[0] = (short)f2bf(v0.x); o8[1] = (short)f2bf(v0.y);
  o8[2] = (short)f2bf(v0.z); o8[3] = (short)f2bf(v0.w);
  o8[4] = (short)f2bf(v1.x); o8[5] = (short)f2bf(v1.y);
  o8[6] = (short)f2bf(v1.z); o8[7] = (short)f2bf(v1.w);
  *(short8*)&Bt2[(size_t)c * 8] = o8;
}

// ---------- MFMA channel mix (unchanged, 16x16x32) ----------
template<int IN_BF16>
__global__ __launch_bounds__(256, 2)
void mix_mfma(const void* __restrict__ in, const ushort_t* __restrict__ thA,
              ushort_t* __restrict__ Y, int b0) {
  const int bid = blockIdx.x;           // nb*48: [bt][mq]
  const int mq = bid & 3;
  const int bt = bid >> 2;              // bl*12 + t
  const int bl = bt / 12, t = bt % 12;
  const int b = b0 + bl;
  const int tid = threadIdx.x;
  const int wv = tid >> 6, lane = tid & 63;
  const int l15 = lane & 15, l4 = lane >> 4;
  const int m0 = mq * 256 + wv * 64;

  const ushort_t* xg_b = (const ushort_t*)in;
  const float*    xg_f = (const float*)in;

  short8 bfr[4][2];
  #pragma unroll
  for (int mf = 0; mf < 4; ++mf) {
    const int m = m0 + mf * 16 + l15;
    #pragma unroll
    for (int ks = 0; ks < 2; ++ks) {
      #pragma unroll
      for (int j = 0; j < 8; ++j) {
        const int i = ks * 32 + l4 * 8 + j;
        const size_t adr = ((size_t)(b * C_ + i) * T_ + t) * N_ + m;
        ushort_t v = IN_BF16 ? xg_b[adr] : f2bf(xg_f[adr]);
        bfr[mf][ks][j] = (short)v;
      }
    }
  }

  const size_t rbase = (size_t)(bt * C_);
  #pragma unroll
  for (int k = 0; k < 3; ++k) {
    short8 afr[4][2];
    #pragma unroll
    for (int of = 0; of < 4; ++of)
      #pragma unroll
      for (int ks = 0; ks < 2; ++ks)
        afr[of][ks] = *(const short8*)&thA[(size_t)(k * 64 + of * 16 + l15) * 64 + ks * 32 + l4 * 8];

    f32x4 acc[4][4] = {};
    #pragma unroll
    for (int ks = 0; ks < 2; ++ks)
      #pragma unroll
      for (int of = 0; of < 4; ++of)
        #pragma unroll
        for (int mf = 0; mf < 4; ++mf)
          acc[of][mf] = __builtin_amdgcn_mfma_f32_16x16x32_bf16(afr[of][ks], bfr[mf][ks], acc[of][mf], 0, 0, 0);

    #pragma unroll
    for (int of = 0; of < 4; ++of)
      #pragma unroll
      for (int mf = 0; mf < 4; ++mf)
        #pragma unroll
        for (int r = 0; r < 4; ++r) {
          const int o = of * 16 + l4 * 4 + r;
          Y[(rbase + o) * KC_ + k * N_ + m0 + mf * 16 + l15] = f2bf(acc[of][mf][r]);
        }
  }
}

// ---------- 192x256-tile GEMM with 32x32x16 MFMA, fragment-major LDS ----------
// LDS per buffer (57344 B): A [ks:4][rg:6][lane:64][16B] (24576) then
//                           B [ks:4][cg:8][lane:64][16B] (32768).
// Each fragment = 1KB lane-contiguous (canonical ds_read_b128; no swizzle needed;
// permutation lives in the per-lane global source of global_load_lds).
// Phases p=ks 0..3; per phase: stages (units sealed by prev barrier) -> 5 ds_reads
// -> 6 MFMA -> barrier. Stage plan for tile u+2 into buf[u&1]:
//   ph0: A2,B3(u+1)   ph1: B0(u+2)   ph2: A0,B1(u+2)   ph3: A1,B2(u+2) + vmcnt(5)
// Ledger: prologue tile0(7)+tile1(5), vmcnt(5) = tile0 landed; steady state
// outstanding 7 after ph3 issues, vmcnt(5) drains A2,B3(u+1); tail vmcnt(0).

#define MM32(a, b, c) __builtin_amdgcn_mfma_f32_32x32x16_bf16(a, b, c, 0, 0, 0)

#define STAGE_A(kt, j) gload16(gA##j + (size_t)(kt) * 64,                       \
    (ushort_t*)(lp + (((kt) & 1) ? LBUF : 0) + (j) * 8192 + wofs))
#define STAGE_B(kt, j) gload16(gBb + (size_t)((kt) * 4 + (j)) * 512,            \
    (ushort_t*)(lp + (((kt) & 1) ? LBUF : 0) + ABYT + (j) * 8192 + wofs))

#define LD8(p) (*(const short8*)(p))

template<int RES_BF16>
__global__ __launch_bounds__(512, 1)
void gemm32(const ushort_t* __restrict__ Y, const ushort_t* __restrict__ Bt2,
            const void* __restrict__ res, const float* __restrict__ bias,
            ushort_t* __restrict__ outb, int batch0) {
  // bijective XCD swizzle; gridDim.x = 16*nb is always a multiple of 8
  const int nwg = gridDim.x;
  int orig = blockIdx.x;
  int q8 = nwg >> 3;
  int wg = (orig & 7) * q8 + (orig >> 3);
  const int mtile = wg >> 2, ntile = wg & 3;

  const int tid = threadIdx.x;
  const int wid = tid >> 6, lane = tid & 63;
  const int wm = wid >> 2, wn = wid & 3;

  __shared__ ushort_t LDSU[LBUF];   // 114688 bytes (2 buffers)
  char* lp = (char*)LDSU;

  const int row0 = mtile * BM_;
  const int n0 = ntile * 256;
  const int wofs = wid * 1024;

  // A staging sources: unit j, wave wid -> frag index f=j*8+wid -> ks=f/6, rg=f%6
  const ushort_t *gA0, *gA1, *gA2;
  {
    int f, ks, rg;
    f = 0 + wid;  ks = f / 6; rg = f % 6;
    gA0 = Y + (size_t)(row0 + rg * 32 + (lane & 31)) * KC_ + ks * 16 + ((lane >> 5) << 3);
    f = 8 + wid;  ks = f / 6; rg = f % 6;
    gA1 = Y + (size_t)(row0 + rg * 32 + (lane & 31)) * KC_ + ks * 16 + ((lane >> 5) << 3);
    f = 16 + wid; ks = f / 6; rg = f % 6;
    gA2 = Y + (size_t)(row0 + rg * 32 + (lane & 31)) * KC_ + ks * 16 + ((lane >> 5) << 3);
  }
  // B staging source: unit j -> ks=j, cg=wid (lane-contiguous 1KB in Bt2)
  const ushort_t* gBb = Bt2 + (size_t)(ntile * 8 + wid) * 98304 + lane * 8;

  // read-side byte bases
  const char* lpA = lp + lane * 16 + wm * 3072;           // + bsel + p*6144 + r*1024
  const char* lpB = lp + ABYT + lane * 16 + wn * 2048;    // + bsel + p*8192 + c*1024

  // prologue: tile0 all 7 units; tile1 minus A2,B3 (those staged at ph0(0))
  STAGE_B(0, 0); STAGE_B(0, 1); STAGE_B(0, 2); STAGE_B(0, 3);
  STAGE_A(0, 0); STAGE_A(0, 1); STAGE_A(0, 2);
  STAGE_B(1, 0); STAGE_B(1, 1); STAGE_B(1, 2);
  STAGE_A(1, 0); STAGE_A(1, 1);
  asm volatile("s_waitcnt vmcnt(5)" ::: "memory");   // tile0 landed
  __builtin_amdgcn_sched_barrier(0);
  __builtin_amdgcn_s_barrier();

  f32x16 acc[3][2] = {};

  for (int u = 0; u < NT_; ++u) {
    const int bsel = (u & 1) ? LBUF : 0;
    #pragma unroll
    for (int p = 0; p < 4; ++p) {
      // stages whose target regions were sealed by the previous barrier
      if (p == 0) {
        if (u + 1 < NT_) { STAGE_A(u + 1, 2); STAGE_B(u + 1, 3); }
      } else if (p == 1) {
        if (u + 2 < NT_) { STAGE_B(u + 2, 0); }
      } else if (p == 2) {
        if (u + 2 < NT_) { STAGE_A(u + 2, 0); STAGE_B(u + 2, 1); }
      } else {
        if (u + 2 < NT_) { STAGE_A(u + 2, 1); STAGE_B(u + 2, 2); }
      }
      // fragment reads for this ks-phase (lane-contiguous 1KB each)
      short8 af0 = LD8(lpA + bsel + p * 6144);
      short8 af1 = LD8(lpA + bsel + p * 6144 + 1024);
      short8 af2 = LD8(lpA + bsel + p * 6144 + 2048);
      short8 bf0 = LD8(lpB + bsel + p * 8192);
      short8 bf1 = LD8(lpB + bsel + p * 8192 + 1024);
      __builtin_amdgcn_s_setprio(1);
      acc[0][0] = MM32(af0, bf0, acc[0][0]);
      acc[0][1] = MM32(af0, bf1, acc[0][1]);
      acc[1][0] = MM32(af1, bf0, acc[1][0]);
      acc[1][1] = MM32(af1, bf1, acc[1][1]);
      acc[2][0] = MM32(af2, bf0, acc[2][0]);
      acc[2][1] = MM32(af2, bf1, acc[2][1]);
      __builtin_amdgcn_s_setprio(0);
      if (p == 3) {
        if (u + 2 < NT_) {
          asm volatile("s_waitcnt vmcnt(5)" ::: "memory");  // tile u+1 complete
        } else {
          asm volatile("s_waitcnt vmcnt(0)" ::: "memory");  // tail drain
        }
        __builtin_amdgcn_sched_barrier(0);
      }
      __builtin_amdgcn_s_barrier();
    }
  }

  // epilogue: bias + residual + relu, bf16 store
  // C/D 32x32 layout: col = lane&31, row = (reg&3) + 8*(reg>>2) + 4*(lane>>5)
  const float*    resf = (const float*)res;
  const ushort_t* resb = (const ushort_t*)res;
  const int gb = batch0 + (mtile >> 2);
  const int rowb0 = (mtile & 3) * BM_ + wm * 96;
  const int l31 = lane & 31, lh = lane >> 5;
  #pragma unroll
  for (int rg = 0; rg < 3; ++rg) {
    #pragma unroll
    for (int cg = 0; cg < 2; ++cg) {
      const int col = n0 + wn * 64 + cg * 32 + l31;
      #pragma unroll
      for (int reg = 0; reg < 16; ++reg) {
        int rif = (reg & 3) + 8 * (reg >> 2) + 4 * lh;
        int rowb = rowb0 + rg * 32 + rif;
        int t = rowb >> 6, o = rowb & 63;
        size_t base = ((size_t)(gb * C_ + o) * T_ + t) * N_;
        float rv = RES_BF16 ? bf2f(resb[base + col]) : resf[base + col];
        float v = acc[rg][cg][reg] + bias[o] + rv;
        v = fmaxf(v, 0.0f);
        outb[base + col] = f2bf(v);
      }
    }
  }
}

// ---------- FC: out[b,t,n,o2] = sum_o fw[o2,o]*x2[b,o,t,n] + fb[o2] ----------
__global__ __launch_bounds__(256, 2)
void fc_kernel(const ushort_t* __restrict__ x2, const float* __restrict__ fw,
               const float* __restrict__ fb, float* __restrict__ out) {
  int bid = blockIdx.x;
  int nt = bid & 15, btid = bid >> 4;
  int t = btid % 12, b = btid / 12;
  int n0 = nt << 6;
  int tid = threadIdx.x;
  __shared__ float xt[64 * 64];
  __shared__ float wl[64 * 64];
  #pragma unroll
  for (int j = 0; j < 2; ++j) {
    int c = tid + j * 256;
    int row = c >> 3, col = (c & 7) << 3;
    short8 v = *(const short8*)&x2[((b * C_ + row) * T_ + t) * N_ + n0 + col];
    #pragma unroll
    for (int q = 0; q < 8; ++q) xt[row * 64 + col + q] = bf2f((ushort_t)v[q]);
  }
  #pragma unroll
  for (int j = 0; j < 4; ++j) {
    int c = tid + j * 256;
    int o2 = c >> 4, o4 = (c & 15) << 2;
    float4 v = *(const float4*)&fw[o2 * 64 + o4];
    wl[(o4 + 0) * 64 + o2] = v.x; wl[(o4 + 1) * 64 + o2] = v.y;
    wl[(o4 + 2) * 64 + o2] = v.z; wl[(o4 + 3) * 64 + o2] = v.w;
  }
  __syncthreads();
  int p = tid & 31, ng = tid >> 5;
  float a0[8] = {}, a1[8] = {};
  for (int o = 0; o < 64; ++o) {
    float w0 = wl[o * 64 + p], w1 = wl[o * 64 + p + 32];
    float4 xa = *(const float4*)&xt[o * 64 + ng * 8];
    float4 xb = *(const float4*)&xt[o * 64 + ng * 8 + 4];
    float xv[8] = {xa.x, xa.y, xa.z, xa.w, xb.x, xb.y, xb.z, xb.w};
    #pragma unroll
    for (int j = 0; j < 8; ++j) { a0[j] = fmaf(w0, xv[j], a0[j]); a1[j] = fmaf(w1, xv[j], a1[j]); }
  }
  float fb0 = fb[p], fb1 = fb[p + 32];
  int obase = (b * T_ + t) * N_ + n0 + ng * 8;
  #pragma unroll
  for (int j = 0; j < 8; ++j) {
    out[(obase + j) * 64 + p]      = a0[j] + fb0;
    out[(obase + j) * 64 + p + 32] = a1[j] + fb1;
  }
}

extern "C" void kernel_launch(void* const* d_in, const int* in_sizes, int n_in,
                              void* d_out, int out_size, void* d_ws, size_t ws_size,
                              hipStream_t stream) {
  const float* x   = (const float*)d_in[0];
  const float* Lk  = (const float*)d_in[1];
  const float* th1 = (const float*)d_in[2];
  const float* b1  = (const float*)d_in[3];
  const float* th2 = (const float*)d_in[4];
  const float* b2  = (const float*)d_in[5];
  const float* fcw = (const float*)d_in[6];
  const float* fcb = (const float*)d_in[7];

  char* ws = (char*)d_ws;
  size_t off = 0;
  auto alloc = [&](size_t bytes) { size_t p = off; off += (bytes + 255) & ~(size_t)255; return p; };
  size_t oBt = alloc((size_t)KC_ * N_ * 2);            // 6.29 MB (fragment-packed)
  size_t oTh = alloc((size_t)2 * 3 * 64 * 64 * 2);
  size_t oX2 = alloc((size_t)B_ * C_ * T_ * N_ * 2);
  size_t perB = (size_t)RPB * KC_ * 2;
  size_t avail = ws_size > off ? ws_size - off : 0;
  int NB = (int)(avail / perB);
  if (NB > B_) NB = B_;
  if (NB < 1) NB = 1;

  ushort_t* Bt2 = (ushort_t*)(ws + oBt);
  ushort_t* Th  = (ushort_t*)(ws + oTh);
  ushort_t* X2  = (ushort_t*)(ws + oX2);
  ushort_t* Yb  = (ushort_t*)(ws + off);
  ushort_t* X1  = (ushort_t*)d_out;

  prep_th<<<96, 256, 0, stream>>>(th1, th2, Th);
  prep_bt<<<1536, 256, 0, stream>>>(Lk, Bt2);

  for (int b0 = 0; b0 < B_; b0 += NB) {
    int nb = (b0 + NB <= B_) ? NB : (B_ - b0);
    mix_mfma<0><<<nb * 48, 256, 0, stream>>>((const void*)x, Th, Yb, b0);
    gemm32<0><<<dim3(16 * nb), 512, 0, stream>>>(Yb, Bt2, (const void*)x, b1, X1, b0);
  }
  for (int b0 = 0; b0 < B_; b0 += NB) {
    int nb = (b0 + NB <= B_) ? NB : (B_ - b0);
    mix_mfma<1><<<nb * 48, 256, 0, stream>>>((const void*)X1, Th + 12288, Yb, b0);
    gemm32<1><<<dim3(16 * nb), 512, 0, stream>>>(Yb, Bt2, (const void*)X1, b2, X2, b0);
  }
  fc_kernel<<<32 * 12 * 16, 256, 0, stream>>>(X2, fcw, fcb, (float*)d_out);
}